// Round 2
// baseline (383.527 us; speedup 1.0000x reference)
//
#include <hip/hip_runtime.h>
#include <hip/hip_bf16.h>

#define LQ 30
#define LD 1024
#define EDIM 256
#define NK 11
#define NPAIR (LQ * NK)  // 330
#define QT_STRIDE 32

#if __has_builtin(__builtin_amdgcn_exp2f)
#define EXP2F __builtin_amdgcn_exp2f
#else
#define EXP2F exp2f
#endif

__device__ __forceinline__ float wave_reduce_add(float v) {
#pragma unroll
  for (int o = 32; o > 0; o >>= 1) v += __shfl_xor(v, o);
  return v;
}

__device__ __forceinline__ unsigned short f2bf(float x) {
  unsigned u = __float_as_uint(x);
  unsigned r = (u + 0x7FFFu + ((u >> 16) & 1u)) >> 16;
  return (unsigned short)r;
}

// mu ascending: [-0.9,-0.7,...,0.9,1.0]; sigma[0]=0.001 (pairs with mu=-0.9), else 0.1
__device__ __forceinline__ void kparams(int k, float& mu, float& w) {
  mu = (k == 10) ? 1.0f : fmaf((float)k, 0.2f, -0.9f);
  // w = -log2(e) / (2*sigma^2)
  w = (k == 0) ? -721347.52f : -72.134752f;
}

// Kernel 1: qt[b][e][QT_STRIDE] = l2-normalized q embeddings, transposed per batch.
__global__ __launch_bounds__(256) void build_qt(
    const int* __restrict__ qidx, const float* __restrict__ emb,
    float* __restrict__ qt) {
  const int b = blockIdx.x;
  const int wave = threadIdx.x >> 6, lane = threadIdx.x & 63;
  for (int r = wave; r < LQ; r += 4) {
    const int row = qidx[b * LQ + r];
    const float4 v = *(const float4*)(emb + (size_t)row * EDIM + lane * 4);
    float ss = v.x * v.x + v.y * v.y + v.z * v.z + v.w * v.w;
    ss = wave_reduce_add(ss);
    const float inv = rsqrtf(fmaxf(ss, 1e-12f));
    float* dst = qt + ((size_t)b * EDIM + lane * 4) * QT_STRIDE + r;
    dst[0 * QT_STRIDE] = v.x * inv;
    dst[1 * QT_STRIDE] = v.y * inv;
    dst[2 * QT_STRIDE] = v.z * inv;
    dst[3 * QT_STRIDE] = v.w * inv;
  }
}

template <int NPASS, bool USE_WS>
__global__ __launch_bounds__(512) void knrm_main(
    const int* __restrict__ qidx, const int* __restrict__ didx,
    const float* __restrict__ emb, const float* __restrict__ qt,
    const float* __restrict__ W, const float* __restrict__ bptr,
    float* __restrict__ out) {
  constexpr int PASS_D = LD / NPASS;          // 512 (ws) or 256 (fallback)
  constexpr int SIMW = PASS_D + 8;            // pad: stride 520/264 floats (bank-safe)
  constexpr int NCHUNK = PASS_D / 128;        // 4 or 2
  constexpr int NITEM = NPAIR * NCHUNK;       // 1320 or 660
  constexpr int NITER = (NITEM + 511) / 512;  // 3 or 2
  constexpr int QBF_STRIDE = 40;              // bf16 fallback: 80B rows, 16B-aligned

  const int b = blockIdx.x;
  const int tid = threadIdx.x;
  const int wave = tid >> 6, lane = tid & 63;

  __shared__ float sim[LQ][SIMW];
  __shared__ float pool[NPAIR];
  __shared__ float red[8];
  __shared__ unsigned short qbf[USE_WS ? 2 : EDIM * QBF_STRIDE];

  if (tid < NPAIR) pool[tid] = 0.0f;

  if constexpr (!USE_WS) {
    // stage l2-normalized q as bf16, transposed [e][QBF_STRIDE]
    for (int r = wave; r < LQ; r += 8) {
      const int row = qidx[b * LQ + r];
      const float4 v = *(const float4*)(emb + (size_t)row * EDIM + lane * 4);
      float ss = v.x * v.x + v.y * v.y + v.z * v.z + v.w * v.w;
      ss = wave_reduce_add(ss);
      const float inv = rsqrtf(fmaxf(ss, 1e-12f));
      const float vals[4] = {v.x * inv, v.y * inv, v.z * inv, v.w * inv};
#pragma unroll
      for (int j = 0; j < 4; ++j)
        qbf[(lane * 4 + j) * QBF_STRIDE + r] = f2bf(vals[j]);
    }
  }
  __syncthreads();

  float part[NITER];
#pragma unroll
  for (int i = 0; i < NITER; ++i) part[i] = 0.0f;

  for (int pass = 0; pass < NPASS; ++pass) {
    // ---------------- phase A: sims for this pass's PASS_D docs ----------------
    if (tid < PASS_D) {
      const int gd = pass * PASS_D + tid;
      const int row = didx[b * LD + gd];
      const float* dbase = emb + (size_t)row * EDIM;
      float acc[LQ];
#pragma unroll
      for (int q2 = 0; q2 < LQ; ++q2) acc[q2] = 0.0f;
      float ss = 0.0f;
      float4 cur[4];
#pragma unroll
      for (int i = 0; i < 4; ++i) cur[i] = *(const float4*)(dbase + i * 4);
      for (int ec = 0; ec < EDIM; ec += 16) {
        float4 nxt[4];
        const int en = (ec + 16) & (EDIM - 1);  // wraps to 0 on last iter (unused)
#pragma unroll
        for (int i = 0; i < 4; ++i)
          nxt[i] = *(const float4*)(dbase + en + i * 4);
#pragma unroll
        for (int i = 0; i < 4; ++i) {
          const float vv[4] = {cur[i].x, cur[i].y, cur[i].z, cur[i].w};
#pragma unroll
          for (int c = 0; c < 4; ++c) {
            const int e = ec + i * 4 + c;
            const float v = vv[c];
            ss = fmaf(v, v, ss);
            if constexpr (USE_WS) {
              // uniform address -> s_load; FMA with scalar operand
              const float* qe = qt + ((size_t)b * EDIM + e) * QT_STRIDE;
#pragma unroll
              for (int q2 = 0; q2 < LQ; ++q2)
                acc[q2] = fmaf(v, qe[q2], acc[q2]);
            } else {
              const unsigned short* qe = &qbf[e * QBF_STRIDE];
#pragma unroll
              for (int q2 = 0; q2 < LQ; ++q2) {
                const float qv = __uint_as_float(((unsigned)qe[q2]) << 16);
                acc[q2] = fmaf(v, qv, acc[q2]);
              }
            }
          }
        }
#pragma unroll
        for (int i = 0; i < 4; ++i) cur[i] = nxt[i];
      }
      const float inv = rsqrtf(fmaxf(ss, 1e-12f));
#pragma unroll
      for (int q2 = 0; q2 < LQ; ++q2) sim[q2][tid] = acc[q2] * inv;
    }
    __syncthreads();
    // ---------------- phase B: exp pooling over this pass ----------------
#pragma unroll
    for (int it = 0; it < NITER; ++it) {
      const int item = tid + it * 512;
      if (item < NITEM) {
        const int chunk = item / NPAIR;       // consecutive lanes: same chunk
        const int pr = item - chunk * NPAIR;  // consecutive pairs
        const int q2 = pr / NK;
        const int k = pr - q2 * NK;
        float mu, w;
        kparams(k, mu, w);
        const float* srow = &sim[q2][chunk * 128];
        float lacc = 0.0f;
#pragma unroll 8
        for (int j = 0; j < 128; j += 4) {
          const float4 s4 = *(const float4*)(srow + j);
          { const float u = s4.x - mu; lacc += EXP2F(u * u * w); }
          { const float u = s4.y - mu; lacc += EXP2F(u * u * w); }
          { const float u = s4.z - mu; lacc += EXP2F(u * u * w); }
          { const float u = s4.w - mu; lacc += EXP2F(u * u * w); }
        }
        part[it] += lacc;
      }
    }
    __syncthreads();
  }

  // merge partial pools
#pragma unroll
  for (int it = 0; it < NITER; ++it) {
    const int item = tid + it * 512;
    if (item < NITEM) {
      const int chunk = item / NPAIR;
      const int pr = item - chunk * NPAIR;
      atomicAdd(&pool[pr], part[it]);
    }
  }
  __syncthreads();

  // log, weight, block-reduce
  float v = 0.0f;
  if (tid < NPAIR) {
    const int q2 = tid / NK;
    const int k = tid - q2 * NK;
    v = logf(fmaxf(pool[tid], 1e-10f)) * 0.01f * W[k];
  }
  v = wave_reduce_add(v);
  if (lane == 0) red[wave] = v;
  __syncthreads();
  if (tid == 0) {
    float t = 0.0f;
#pragma unroll
    for (int w2 = 0; w2 < 8; ++w2) t += red[w2];
    out[b] = t + bptr[0];
  }
}

extern "C" void kernel_launch(void* const* d_in, const int* in_sizes, int n_in,
                              void* d_out, int out_size, void* d_ws, size_t ws_size,
                              hipStream_t stream) {
  (void)n_in;
  (void)out_size;
  const int* qidx = (const int*)d_in[0];
  const int* didx = (const int*)d_in[1];
  const float* emb = (const float*)d_in[2];
  const float* W = (const float*)d_in[3];
  const float* bptr = (const float*)d_in[4];
  float* out = (float*)d_out;

  const int B = in_sizes[0] / LQ;  // 256
  const size_t qt_bytes = (size_t)B * EDIM * QT_STRIDE * sizeof(float);

  if (ws_size >= qt_bytes) {
    float* qt = (float*)d_ws;
    build_qt<<<B, 256, 0, stream>>>(qidx, emb, qt);
    knrm_main<2, true><<<B, 512, 0, stream>>>(qidx, didx, emb, qt, W, bptr, out);
  } else {
    knrm_main<4, false><<<B, 512, 0, stream>>>(qidx, didx, emb, nullptr, W, bptr, out);
  }
}